// Round 11
// baseline (399.459 us; speedup 1.0000x reference)
//
#include <hip/hip_runtime.h>
#include <math.h>

#define N_NODES 4096
#define B_GR 4
#define FIN_K 354
#define K1P 384
#define HID 352
#define NHEAD 4
#define PH 88
#define E_EDGES 65536
#define ETOT (E_EDGES + N_NODES)
#define EPSV 1e-5f
#define SLOPE 0.2f
#define SPLITS 64

typedef unsigned short u16;
typedef unsigned int u32;
typedef __attribute__((ext_vector_type(8))) short bf16x8;
typedef __attribute__((ext_vector_type(4))) float f32x4;

__device__ __forceinline__ void split_bf16(float v, u16& hi, u16& lo) {
    u32 u = __float_as_uint(v);
    hi = (u16)(u >> 16);
    float rem = v - __uint_as_float(((u32)hi) << 16);
    lo = (u16)(__float_as_uint(rem) >> 16);
}

__device__ __forceinline__ u16 bf16_rne(float v) {
    u32 u = __float_as_uint(v);
    u32 r = u + 0x7FFFu + ((u >> 16) & 1u);
    return (u16)(r >> 16);
}

// ---------------- CSR build ----------------
__global__ void k_zero3(int* __restrict__ cnt, int* __restrict__ cur, int* __restrict__ ctr) {
    int i = blockIdx.x * blockDim.x + threadIdx.x;
    if (i < N_NODES) { cnt[i] = 0; cur[i] = 0; }
    if (i < 8) ctr[i] = 0;
}

__global__ void k_hist(const int* __restrict__ ei, int* __restrict__ cnt) {
    int e = blockIdx.x * blockDim.x + threadIdx.x;
    if (e >= ETOT) return;
    int dst = (e < E_EDGES) ? ei[E_EDGES + e] : (e - E_EDGES);
    atomicAdd(&cnt[dst], 1);
}

__global__ void k_scan(const int* __restrict__ cnt, int* __restrict__ rp) {
    __shared__ int tot[256];
    int t = threadIdx.x;
    int base = t * 16;
    int loc[16];
    int s = 0;
    #pragma unroll
    for (int i = 0; i < 16; i++) { loc[i] = s; s += cnt[base + i]; }
    tot[t] = s;
    __syncthreads();
    for (int off = 1; off < 256; off <<= 1) {
        int v = (t >= off) ? tot[t - off] : 0;
        __syncthreads();
        tot[t] += v;
        __syncthreads();
    }
    int excl = (t == 0) ? 0 : tot[t - 1];
    #pragma unroll
    for (int i = 0; i < 16; i++) rp[base + i] = excl + loc[i];
    if (t == 255) rp[N_NODES] = tot[255];
}

__global__ void k_scatter(const int* __restrict__ ei, const int* __restrict__ rp,
                          int* __restrict__ cur, int* __restrict__ col) {
    int e = blockIdx.x * blockDim.x + threadIdx.x;
    if (e >= ETOT) return;
    int src, dst;
    if (e < E_EDGES) { src = ei[e]; dst = ei[E_EDGES + e]; }
    else { src = e - E_EDGES; dst = src; }
    int pos = rp[dst] + atomicAdd(&cur[dst], 1);
    col[pos] = src;
}

// ---------------- input conversion: x[B][FIN][N] -> XT hi/lo [B][N][384] ----------------
__global__ __launch_bounds__(256) void k_prep_x(const float* __restrict__ x,
                                                u16* __restrict__ xth, u16* __restrict__ xtl) {
    __shared__ float tile[64][65];
    int b = blockIdx.z;
    int n0 = blockIdx.x * 64;
    int k0 = blockIdx.y * 64;
    int tid = threadIdx.x;
    int r = tid >> 2;
    int cq = (tid & 3) * 16;
    int kglob = k0 + r;
    if (kglob < FIN_K) {
        const float* src = x + ((size_t)b * FIN_K + kglob) * N_NODES + n0 + cq;
        float4 v0 = *reinterpret_cast<const float4*>(src + 0);
        float4 v1 = *reinterpret_cast<const float4*>(src + 4);
        float4 v2 = *reinterpret_cast<const float4*>(src + 8);
        float4 v3 = *reinterpret_cast<const float4*>(src + 12);
        *reinterpret_cast<float4*>(&tile[r][cq + 0]) = v0;
        *reinterpret_cast<float4*>(&tile[r][cq + 4]) = v1;
        *reinterpret_cast<float4*>(&tile[r][cq + 8]) = v2;
        *reinterpret_cast<float4*>(&tile[r][cq + 12]) = v3;
    } else {
        float4 z = make_float4(0.f, 0.f, 0.f, 0.f);
        *reinterpret_cast<float4*>(&tile[r][cq + 0]) = z;
        *reinterpret_cast<float4*>(&tile[r][cq + 4]) = z;
        *reinterpret_cast<float4*>(&tile[r][cq + 8]) = z;
        *reinterpret_cast<float4*>(&tile[r][cq + 12]) = z;
    }
    __syncthreads();
    int nr = tid >> 2;
    int kq = (tid & 3) * 16;
    u16 hb[16], lb[16];
    #pragma unroll
    for (int i = 0; i < 16; i++) split_bf16(tile[kq + i][nr], hb[i], lb[i]);
    size_t o = ((size_t)b * N_NODES + n0 + nr) * K1P + k0 + kq;
    *reinterpret_cast<uint4*>(xth + o)     = *reinterpret_cast<uint4*>(hb);
    *reinterpret_cast<uint4*>(xth + o + 8) = *reinterpret_cast<uint4*>(hb + 8);
    *reinterpret_cast<uint4*>(xtl + o)     = *reinterpret_cast<uint4*>(lb);
    *reinterpret_cast<uint4*>(xtl + o + 8) = *reinterpret_cast<uint4*>(lb + 8);
}

// ---------------- unified weight prep: base rows 0..351, logit rows 352..359, zero 360..383 ----------------
__global__ void k_prep_wall(const float* __restrict__ W0, const float* __restrict__ W1, const float* __restrict__ W2,
                            const float* __restrict__ as0, const float* __restrict__ as1, const float* __restrict__ as2,
                            const float* __restrict__ ad0, const float* __restrict__ ad1, const float* __restrict__ ad2,
                            u16* __restrict__ h0, u16* __restrict__ l0,
                            u16* __restrict__ h1, u16* __restrict__ l1,
                            u16* __restrict__ h2, u16* __restrict__ l2) {
    int l = blockIdx.y;
    const float* W   = (l == 0) ? W0 : (l == 1) ? W1 : W2;
    const float* as_ = (l == 0) ? as0 : (l == 1) ? as1 : as2;
    const float* ad_ = (l == 0) ? ad0 : (l == 1) ? ad1 : ad2;
    u16* wth = (l == 0) ? h0 : (l == 1) ? h1 : h2;
    u16* wtl = (l == 0) ? l0 : (l == 1) ? l1 : l2;
    int K  = (l == 0) ? FIN_K : HID;
    int KP = (l == 0) ? K1P : HID;
    int n = blockIdx.x;   // 0..383
    if (n < HID) {
        for (int k = threadIdx.x; k < KP; k += 64) {
            float v = (k < K) ? W[(size_t)k * HID + n] : 0.f;
            u16 hi, lo;
            split_bf16(v, hi, lo);
            wth[(size_t)n * KP + k] = hi;
            wtl[(size_t)n * KP + k] = lo;
        }
    } else if (n < 360) {
        int which = n - 352;
        int h = which & 3;
        const float* vec = ((which < 4) ? as_ : ad_) + h * PH;
        for (int k = threadIdx.x; k < KP; k += 64) {
            float acc = 0.f;
            if (k < K) {
                const float* wrow = W + (size_t)k * HID + h * PH;
                #pragma unroll 8
                for (int j = 0; j < PH; j++) acc = fmaf(wrow[j], vec[j], acc);
            }
            u16 hi, lo;
            split_bf16(acc, hi, lo);
            wth[(size_t)n * KP + k] = hi;
            wtl[(size_t)n * KP + k] = lo;
        }
    } else {
        for (int k = threadIdx.x; k < KP; k += 64) {
            wth[(size_t)n * KP + k] = 0;
            wtl[(size_t)n * KP + k] = 0;
        }
    }
}

// ---------------- MFMA GEMM + fused epilogue: bf16 pack + attention logits ----------------
__global__ __launch_bounds__(256) void k_gemm_mfma(
    const u16* __restrict__ Ah, const u16* __restrict__ Al,
    const u16* __restrict__ Bh, const u16* __restrict__ Bl,
    u16* __restrict__ xb16, float* __restrict__ a_s, float* __restrict__ a_d, int K)
{
    __shared__ __align__(16) char smem[24576];
    const int AHo = 0, ALo = 4096, BHo = 8192, BLo = 16384;
    int b = blockIdx.z;
    int m0 = blockIdx.y * 64;
    int n0 = blockIdx.x * 128;
    int tid = threadIdx.x;
    int lane = tid & 63, wid = tid >> 6;
    int wr = (wid >> 1) * 32, wc = (wid & 1) * 64;
    int lrow = lane & 15, kgv = lane >> 4;

    const u16* Abh = Ah + (size_t)b * N_NODES * K;
    const u16* Abl = Al + (size_t)b * N_NODES * K;

    int srow = tid >> 2, skg = tid & 3;
    int sxor = (srow >> 1) & 3;
    int st_lds = srow * 64 + ((skg ^ sxor) << 4);
    int st_lds1 = (srow + 64) * 64 + ((skg ^ sxor) << 4);
    size_t a_g  = (size_t)(m0 + srow) * K + skg * 8;
    size_t b_g0 = (size_t)(n0 + srow) * K + skg * 8;
    size_t b_g1 = (size_t)(n0 + srow + 64) * K + skg * 8;

    int a_ad[2], b_ad[4];
    #pragma unroll
    for (int mf = 0; mf < 2; mf++) {
        int r = wr + mf * 16 + lrow;
        a_ad[mf] = r * 64 + ((kgv ^ ((r >> 1) & 3)) << 4);
    }
    #pragma unroll
    for (int nf = 0; nf < 4; nf++) {
        int c = wc + nf * 16 + lrow;
        b_ad[nf] = c * 64 + ((kgv ^ ((c >> 1) & 3)) << 4);
    }

    f32x4 acc[2][4];
    #pragma unroll
    for (int i = 0; i < 2; i++)
        #pragma unroll
        for (int j = 0; j < 4; j++) acc[i][j] = (f32x4){0.f, 0.f, 0.f, 0.f};

    uint4 cah = *(const uint4*)(Abh + a_g);
    uint4 cal = *(const uint4*)(Abl + a_g);
    uint4 cbh0 = *(const uint4*)(Bh + b_g0);
    uint4 cbl0 = *(const uint4*)(Bl + b_g0);
    uint4 cbh1 = *(const uint4*)(Bh + b_g1);
    uint4 cbl1 = *(const uint4*)(Bl + b_g1);

    for (int k0 = 0; k0 < K; k0 += 32) {
        __syncthreads();
        *(uint4*)(smem + AHo + st_lds) = cah;
        *(uint4*)(smem + ALo + st_lds) = cal;
        *(uint4*)(smem + BHo + st_lds) = cbh0;
        *(uint4*)(smem + BLo + st_lds) = cbl0;
        *(uint4*)(smem + BHo + st_lds1) = cbh1;
        *(uint4*)(smem + BLo + st_lds1) = cbl1;
        int k1 = k0 + 32;
        uint4 nah, nal, nbh0, nbl0, nbh1, nbl1;
        bool more = k1 < K;
        if (more) {
            nah = *(const uint4*)(Abh + a_g + k1);
            nal = *(const uint4*)(Abl + a_g + k1);
            nbh0 = *(const uint4*)(Bh + b_g0 + k1);
            nbl0 = *(const uint4*)(Bl + b_g0 + k1);
            nbh1 = *(const uint4*)(Bh + b_g1 + k1);
            nbl1 = *(const uint4*)(Bl + b_g1 + k1);
        }
        __syncthreads();

        bf16x8 fah0 = *(const bf16x8*)(smem + AHo + a_ad[0]);
        bf16x8 fah1 = *(const bf16x8*)(smem + AHo + a_ad[1]);
        bf16x8 fal0 = *(const bf16x8*)(smem + ALo + a_ad[0]);
        bf16x8 fal1 = *(const bf16x8*)(smem + ALo + a_ad[1]);
        #pragma unroll
        for (int nf = 0; nf < 4; nf++) {
            bf16x8 fbh = *(const bf16x8*)(smem + BHo + b_ad[nf]);
            bf16x8 fbl = *(const bf16x8*)(smem + BLo + b_ad[nf]);
            acc[0][nf] = __builtin_amdgcn_mfma_f32_16x16x32_bf16(fah0, fbh, acc[0][nf], 0, 0, 0);
            acc[1][nf] = __builtin_amdgcn_mfma_f32_16x16x32_bf16(fah1, fbh, acc[1][nf], 0, 0, 0);
            acc[0][nf] = __builtin_amdgcn_mfma_f32_16x16x32_bf16(fal0, fbh, acc[0][nf], 0, 0, 0);
            acc[1][nf] = __builtin_amdgcn_mfma_f32_16x16x32_bf16(fal1, fbh, acc[1][nf], 0, 0, 0);
            acc[0][nf] = __builtin_amdgcn_mfma_f32_16x16x32_bf16(fah0, fbl, acc[0][nf], 0, 0, 0);
            acc[1][nf] = __builtin_amdgcn_mfma_f32_16x16x32_bf16(fah1, fbl, acc[1][nf], 0, 0, 0);
        }
        if (more) { cah = nah; cal = nal; cbh0 = nbh0; cbl0 = nbl0; cbh1 = nbh1; cbl1 = nbl1; }
    }

    #pragma unroll
    for (int nf = 0; nf < 4; nf++) {
        int colg = n0 + wc + nf * 16 + lrow;
        if (colg < HID) {
            #pragma unroll
            for (int mf = 0; mf < 2; mf++) {
                #pragma unroll
                for (int r = 0; r < 4; r++) {
                    int rowg = m0 + wr + mf * 16 + kgv * 4 + r;
                    xb16[((size_t)b * N_NODES + rowg) * HID + colg] = bf16_rne(acc[mf][nf][r]);
                }
            }
        } else if (colg < 360) {
            int which = colg - 352;
            float* dbuf = (which < 4) ? a_s : a_d;
            int hsel = which & 3;
            #pragma unroll
            for (int mf = 0; mf < 2; mf++) {
                #pragma unroll
                for (int r = 0; r < 4; r++) {
                    int rowg = m0 + wr + mf * 16 + kgv * 4 + r;
                    dbuf[((size_t)b * N_NODES + rowg) * 4 + hsel] = acc[mf][nf][r];
                }
            }
        }
    }
}

// ---------------- wave-per-dst aggregation: no LDS, no barriers ----------------
__global__ __launch_bounds__(256) void k_agg(
    const u16* __restrict__ xb16, const float* __restrict__ asrc,
    const float* __restrict__ adst, const int* __restrict__ rp,
    const int* __restrict__ col, const float* __restrict__ bias,
    float* __restrict__ g)
{
    int id = blockIdx.x;
    int xcd = id & 7;
    int gr = xcd >> 1;
    int w = threadIdx.x >> 6;
    int l = threadIdx.x & 63;
    int dst = ((((id >> 3) << 1) | (xcd & 1)) << 2) + w;
    int h = l & 3, slot = l >> 2;
    int beg = rp[dst];
    int deg = rp[dst + 1] - beg;
    const float* asG = asrc + (size_t)gr * N_NODES * NHEAD;
    float my_adst = adst[((size_t)gr * N_NODES + dst) * 4 + h];
    const u32* xb = reinterpret_cast<const u32*>(xb16) + (size_t)gr * N_NODES * 176;

    int c1 = l + 64, c2 = l + 128;
    int hh0 = l / 44, hh1 = c1 / 44, hh2 = c2 / 44;
    bool has2 = (l < 48);
    float2 a0 = {0.f, 0.f}, a1 = {0.f, 0.f}, a2 = {0.f, 0.f};
    float den = 0.f;

    for (int c0 = 0; c0 < deg; c0 += 16) {
        int nthis = min(16, deg - c0);
        int sIdx = col[beg + c0 + ((slot < nthis) ? slot : 0)];
        float xv = asG[sIdx * 4 + h] + my_adst;
        float lg = (xv > 0.f) ? xv : SLOPE * xv;
        float e = (slot < nthis) ? expf(lg) : 0.f;
        den += e;
        int off = sIdx * 176;
        #pragma unroll 2
        for (int i = 0; i < nthis; i++) {
            int offi = __shfl(off, i << 2);
            float e0 = __shfl(e, (i << 2) | hh0);
            float e1 = __shfl(e, (i << 2) | hh1);
            u32 v0 = xb[offi + l];
            u32 v1 = xb[offi + c1];
            a0.x = fmaf(e0, __uint_as_float(v0 << 16), a0.x);
            a0.y = fmaf(e0, __uint_as_float(v0 & 0xFFFF0000u), a0.y);
            a1.x = fmaf(e1, __uint_as_float(v1 << 16), a1.x);
            a1.y = fmaf(e1, __uint_as_float(v1 & 0xFFFF0000u), a1.y);
            if (has2) {
                float e2 = __shfl(e, (i << 2) | hh2);
                u32 v2 = xb[offi + c2];
                a2.x = fmaf(e2, __uint_as_float(v2 << 16), a2.x);
                a2.y = fmaf(e2, __uint_as_float(v2 & 0xFFFF0000u), a2.y);
            }
        }
    }

    den += __shfl_xor(den, 4);
    den += __shfl_xor(den, 8);
    den += __shfl_xor(den, 16);
    den += __shfl_xor(den, 32);
    float inv = 1.0f / den;
    float i0 = __shfl(inv, hh0);
    float i1 = __shfl(inv, hh1);
    float* grow = g + ((size_t)gr * N_NODES + dst) * HID;
    float2 b0 = *reinterpret_cast<const float2*>(bias + 2 * l);
    float2 b1 = *reinterpret_cast<const float2*>(bias + 2 * c1);
    float2 o0 = {a0.x * i0 + b0.x, a0.y * i0 + b0.y};
    float2 o1 = {a1.x * i1 + b1.x, a1.y * i1 + b1.y};
    *reinterpret_cast<float2*>(grow + 2 * l) = o0;
    *reinterpret_cast<float2*>(grow + 2 * c1) = o1;
    if (has2) {
        float i2 = __shfl(inv, hh2);
        float2 b2 = *reinterpret_cast<const float2*>(bias + 2 * c2);
        float2 o2 = {a2.x * i2 + b2.x, a2.y * i2 + b2.y};
        *reinterpret_cast<float2*>(grow + 2 * c2) = o2;
    }
}

// ---------------- fused GraphNorm reduce + finalize (last-block pattern) ----------------
// POOL=false: partial sum/sumsq -> last block computes mu_ms & scale.
// POOL=true : partial sum -> last block computes out[b] = mean(h3) . clfw + clfb.
template<bool POOL>
__global__ __launch_bounds__(384) void k_reduce_norm(
    const float* __restrict__ g, float* __restrict__ ps, float* __restrict__ pss,
    const float* __restrict__ ms, const float* __restrict__ w, const float* __restrict__ cb,
    float* __restrict__ mu_ms, float* __restrict__ scale,
    float* __restrict__ outp, int* __restrict__ ctr)
{
    __shared__ float buf[384];
    __shared__ int lastFlag;
    int b = blockIdx.y, chunk = blockIdx.x;
    int c = threadIdx.x;
    const int ROWS = N_NODES / SPLITS;
    if (c < HID) {
        const float* base = g + ((size_t)b * N_NODES + chunk * ROWS) * HID + c;
        float s = 0.f, ss = 0.f;
        for (int r = 0; r < ROWS; r++) {
            float v = base[(size_t)r * HID];
            s += v;
            if (!POOL) ss = fmaf(v, v, ss);
        }
        ps[((size_t)b * SPLITS + chunk) * HID + c] = s;
        if (!POOL) pss[((size_t)b * SPLITS + chunk) * HID + c] = ss;
    }
    __threadfence();
    __syncthreads();
    if (threadIdx.x == 0) {
        int old = atomicAdd(&ctr[b], 1);
        lastFlag = (old == SPLITS - 1) ? 1 : 0;
    }
    __syncthreads();
    if (!lastFlag) return;
    __threadfence();
    float S = 0.f, SS = 0.f;
    if (c < HID) {
        for (int q = 0; q < SPLITS; q++) {
            S += ps[((size_t)b * SPLITS + q) * HID + c];
            if (!POOL) SS += pss[((size_t)b * SPLITS + q) * HID + c];
        }
    }
    if (POOL) {
        buf[threadIdx.x] = (c < HID) ? (S / (float)N_NODES) * w[c] : 0.f;
        __syncthreads();
        if (threadIdx.x < 64) {
            float acc = 0.f;
            for (int j = threadIdx.x; j < 384; j += 64) acc += buf[j];
            for (int o = 32; o; o >>= 1) acc += __shfl_down(acc, o);
            if (threadIdx.x == 0) outp[b] = acc + cb[0];
        }
    } else if (c < HID) {
        float mu = S / (float)N_NODES;
        float Eh2 = SS / (float)N_NODES;
        float msv = ms[c];
        float var = Eh2 - 2.f * msv * mu * mu + msv * msv * mu * mu;
        float rstd = 1.0f / sqrtf(var + EPSV);
        mu_ms[b * HID + c] = msv * mu;
        scale[b * HID + c] = rstd * w[c];
    }
    if (threadIdx.x == 0) ctr[b] = 0;   // self-reset for next use
}

// ---------------- apply: norm + residual(from hi/lo) + relu; writes bf16 hi/lo (+opt fp32) ----------------
template<bool RES, bool WBF, bool WOUT>
__global__ void k_apply(const float* __restrict__ g,
                        const float* __restrict__ mu_ms, const float* __restrict__ scale,
                        const float* __restrict__ gnb, float* __restrict__ hout,
                        u16* __restrict__ hh, u16* __restrict__ hl) {
    size_t i2 = (size_t)blockIdx.x * blockDim.x + threadIdx.x;
    size_t total2 = (size_t)B_GR * N_NODES * HID / 2;
    if (i2 >= total2) return;
    size_t e = i2 * 2;
    int c = (int)(e % HID);
    int b = (int)(e / ((size_t)N_NODES * HID));
    float2 v = *reinterpret_cast<const float2*>(g + e);
    float2 mm = *reinterpret_cast<const float2*>(mu_ms + b * HID + c);
    float2 sc = *reinterpret_cast<const float2*>(scale + b * HID + c);
    float2 gb2 = *reinterpret_cast<const float2*>(gnb + c);
    float o0 = (v.x - mm.x) * sc.x + gb2.x;
    float o1 = (v.y - mm.y) * sc.y + gb2.y;
    if (RES) {
        u32 ph = *reinterpret_cast<const u32*>(hh + e);
        u32 pl = *reinterpret_cast<const u32*>(hl + e);
        o0 += __uint_as_float((ph & 0xFFFFu) << 16) + __uint_as_float((pl & 0xFFFFu) << 16);
        o1 += __uint_as_float(ph & 0xFFFF0000u) + __uint_as_float(pl & 0xFFFF0000u);
    }
    o0 = fmaxf(o0, 0.f);
    o1 = fmaxf(o1, 0.f);
    if (WOUT) *reinterpret_cast<float2*>(hout + e) = make_float2(o0, o1);
    if (WBF) {
        u16 h0, l0, h1, l1;
        split_bf16(o0, h0, l0);
        split_bf16(o1, h1, l1);
        *reinterpret_cast<u32*>(hh + e) = (u32)h0 | ((u32)h1 << 16);
        *reinterpret_cast<u32*>(hl + e) = (u32)l0 | ((u32)l1 << 16);
    }
}

extern "C" void kernel_launch(void* const* d_in, const int* in_sizes, int n_in,
                              void* d_out, int out_size, void* d_ws, size_t ws_size,
                              hipStream_t stream) {
    const float* x = (const float*)d_in[0];
    const int* ei = (const int*)d_in[1];
    const float* W[3]   = {(const float*)d_in[2],  (const float*)d_in[9],  (const float*)d_in[16]};
    const float* as_[3] = {(const float*)d_in[3],  (const float*)d_in[10], (const float*)d_in[17]};
    const float* ad_[3] = {(const float*)d_in[4],  (const float*)d_in[11], (const float*)d_in[18]};
    const float* bi[3]  = {(const float*)d_in[5],  (const float*)d_in[12], (const float*)d_in[19]};
    const float* gw[3]  = {(const float*)d_in[6],  (const float*)d_in[13], (const float*)d_in[20]};
    const float* gb[3]  = {(const float*)d_in[7],  (const float*)d_in[14], (const float*)d_in[21]};
    const float* gms[3] = {(const float*)d_in[8],  (const float*)d_in[15], (const float*)d_in[22]};
    const float* clfw = (const float*)d_in[23];
    const float* clfb = (const float*)d_in[24];
    float* out = (float*)d_out;

    char* ws = (char*)d_ws;
    size_t off = 0;
    auto alloc = [&](size_t bytes) -> void* {
        void* p = ws + off;
        off += (bytes + 255) & ~(size_t)255;
        return p;
    };
    size_t bigf = sizeof(float) * (size_t)B_GR * N_NODES * HID;
    float* gbuf  = (float*)alloc(bigf);
    float* hA    = (float*)alloc(bigf);   // h3 fp32 for pooling
    size_t bfbytes = sizeof(u16) * (size_t)B_GR * N_NODES * K1P;
    u16* bf_hi = (u16*)alloc(bfbytes);
    u16* bf_lo = (u16*)alloc(bfbytes);
    u16* xb16  = (u16*)alloc(sizeof(u16) * (size_t)B_GR * N_NODES * NHEAD * PH);
    u16* wt_h[3]; u16* wt_l[3];
    wt_h[0] = (u16*)alloc(sizeof(u16) * 384 * K1P);
    wt_l[0] = (u16*)alloc(sizeof(u16) * 384 * K1P);
    for (int l = 1; l < 3; l++) {
        wt_h[l] = (u16*)alloc(sizeof(u16) * 384 * HID);
        wt_l[l] = (u16*)alloc(sizeof(u16) * 384 * HID);
    }
    float* a_s   = (float*)alloc(sizeof(float) * B_GR * N_NODES * NHEAD);
    float* a_d   = (float*)alloc(sizeof(float) * B_GR * N_NODES * NHEAD);
    float* ps    = (float*)alloc(sizeof(float) * B_GR * SPLITS * HID);
    float* pss   = (float*)alloc(sizeof(float) * B_GR * SPLITS * HID);
    float* mu_ms = (float*)alloc(sizeof(float) * B_GR * HID);
    float* scale = (float*)alloc(sizeof(float) * B_GR * HID);
    int* rp  = (int*)alloc(sizeof(int) * (N_NODES + 1));
    int* cnt = (int*)alloc(sizeof(int) * N_NODES);
    int* cur = (int*)alloc(sizeof(int) * N_NODES);
    int* col = (int*)alloc(sizeof(int) * ETOT);
    int* ctr = (int*)alloc(sizeof(int) * 8);

    // weight + input prep (2 dispatches)
    k_prep_wall<<<dim3(384, 3), 64, 0, stream>>>(W[0], W[1], W[2],
                                                 as_[0], as_[1], as_[2],
                                                 ad_[0], ad_[1], ad_[2],
                                                 wt_h[0], wt_l[0], wt_h[1], wt_l[1], wt_h[2], wt_l[2]);
    k_prep_x<<<dim3(64, 6, B_GR), 256, 0, stream>>>(x, bf_hi, bf_lo);

    // CSR build (4 dispatches)
    k_zero3<<<(N_NODES + 255) / 256, 256, 0, stream>>>(cnt, cur, ctr);
    k_hist<<<(ETOT + 255) / 256, 256, 0, stream>>>(ei, cnt);
    k_scan<<<1, 256, 0, stream>>>(cnt, rp);
    k_scatter<<<(ETOT + 255) / 256, 256, 0, stream>>>(ei, rp, cur, col);

    dim3 ggrid(3, N_NODES / 64, B_GR);
    dim3 rgrid(SPLITS, B_GR);
    size_t total2 = (size_t)B_GR * N_NODES * HID / 2;
    int ablocks = (int)((total2 + 255) / 256);

    for (int l = 0; l < 3; l++) {
        int K = (l == 0) ? K1P : HID;
        k_gemm_mfma<<<ggrid, 256, 0, stream>>>(bf_hi, bf_lo, wt_h[l], wt_l[l], xb16, a_s, a_d, K);
        k_agg<<<B_GR * N_NODES / 4, 256, 0, stream>>>(xb16, a_s, a_d, rp, col, bi[l], gbuf);
        k_reduce_norm<false><<<rgrid, 384, 0, stream>>>(gbuf, ps, pss, gms[l], gw[l], nullptr,
                                                        mu_ms, scale, nullptr, ctr);
        if (l == 0)      k_apply<false, true,  false><<<ablocks, 256, 0, stream>>>(gbuf, mu_ms, scale, gb[l], hA, bf_hi, bf_lo);
        else if (l == 1) k_apply<true,  true,  false><<<ablocks, 256, 0, stream>>>(gbuf, mu_ms, scale, gb[l], hA, bf_hi, bf_lo);
        else             k_apply<true,  false, true ><<<ablocks, 256, 0, stream>>>(gbuf, mu_ms, scale, gb[l], hA, bf_hi, bf_lo);
    }
    // pool + classifier (1 dispatch)
    k_reduce_norm<true><<<rgrid, 384, 0, stream>>>(hA, ps, pss, nullptr, clfw, clfb,
                                                   nullptr, nullptr, out, ctr);
}

// Round 12
// 277.481 us; speedup vs baseline: 1.4396x; 1.4396x over previous
//
#include <hip/hip_runtime.h>
#include <math.h>

#define N_NODES 4096
#define B_GR 4
#define FIN_K 354
#define K1P 384
#define HID 352
#define NHEAD 4
#define PH 88
#define E_EDGES 65536
#define ETOT (E_EDGES + N_NODES)
#define EPSV 1e-5f
#define SLOPE 0.2f
#define SPLITS 64

typedef unsigned short u16;
typedef unsigned int u32;
typedef __attribute__((ext_vector_type(8))) short bf16x8;
typedef __attribute__((ext_vector_type(4))) float f32x4;

__device__ __forceinline__ void split_bf16(float v, u16& hi, u16& lo) {
    u32 u = __float_as_uint(v);
    hi = (u16)(u >> 16);
    float rem = v - __uint_as_float(((u32)hi) << 16);
    lo = (u16)(__float_as_uint(rem) >> 16);
}

__device__ __forceinline__ u16 bf16_rne(float v) {
    u32 u = __float_as_uint(v);
    u32 r = u + 0x7FFFu + ((u >> 16) & 1u);
    return (u16)(r >> 16);
}

// ---------------- CSR build ----------------
__global__ void k_zero3(int* __restrict__ cnt, int* __restrict__ cur) {
    int i = blockIdx.x * blockDim.x + threadIdx.x;
    if (i < N_NODES) { cnt[i] = 0; cur[i] = 0; }
}

__global__ void k_hist(const int* __restrict__ ei, int* __restrict__ cnt) {
    int e = blockIdx.x * blockDim.x + threadIdx.x;
    if (e >= ETOT) return;
    int dst = (e < E_EDGES) ? ei[E_EDGES + e] : (e - E_EDGES);
    atomicAdd(&cnt[dst], 1);
}

__global__ void k_scan(const int* __restrict__ cnt, int* __restrict__ rp) {
    __shared__ int tot[256];
    int t = threadIdx.x;
    int base = t * 16;
    int loc[16];
    int s = 0;
    #pragma unroll
    for (int i = 0; i < 16; i++) { loc[i] = s; s += cnt[base + i]; }
    tot[t] = s;
    __syncthreads();
    for (int off = 1; off < 256; off <<= 1) {
        int v = (t >= off) ? tot[t - off] : 0;
        __syncthreads();
        tot[t] += v;
        __syncthreads();
    }
    int excl = (t == 0) ? 0 : tot[t - 1];
    #pragma unroll
    for (int i = 0; i < 16; i++) rp[base + i] = excl + loc[i];
    if (t == 255) rp[N_NODES] = tot[255];
}

__global__ void k_scatter(const int* __restrict__ ei, const int* __restrict__ rp,
                          int* __restrict__ cur, int* __restrict__ col) {
    int e = blockIdx.x * blockDim.x + threadIdx.x;
    if (e >= ETOT) return;
    int src, dst;
    if (e < E_EDGES) { src = ei[e]; dst = ei[E_EDGES + e]; }
    else { src = e - E_EDGES; dst = src; }
    int pos = rp[dst] + atomicAdd(&cur[dst], 1);
    col[pos] = src;
}

// ---------------- input conversion: x[B][FIN][N] -> XT hi/lo [B][N][384] ----------------
__global__ __launch_bounds__(256) void k_prep_x(const float* __restrict__ x,
                                                u16* __restrict__ xth, u16* __restrict__ xtl) {
    __shared__ float tile[64][65];
    int b = blockIdx.z;
    int n0 = blockIdx.x * 64;
    int k0 = blockIdx.y * 64;
    int tid = threadIdx.x;
    int r = tid >> 2;
    int cq = (tid & 3) * 16;
    int kglob = k0 + r;
    if (kglob < FIN_K) {
        const float* src = x + ((size_t)b * FIN_K + kglob) * N_NODES + n0 + cq;
        float4 v0 = *reinterpret_cast<const float4*>(src + 0);
        float4 v1 = *reinterpret_cast<const float4*>(src + 4);
        float4 v2 = *reinterpret_cast<const float4*>(src + 8);
        float4 v3 = *reinterpret_cast<const float4*>(src + 12);
        *reinterpret_cast<float4*>(&tile[r][cq + 0]) = v0;
        *reinterpret_cast<float4*>(&tile[r][cq + 4]) = v1;
        *reinterpret_cast<float4*>(&tile[r][cq + 8]) = v2;
        *reinterpret_cast<float4*>(&tile[r][cq + 12]) = v3;
    } else {
        float4 z = make_float4(0.f, 0.f, 0.f, 0.f);
        *reinterpret_cast<float4*>(&tile[r][cq + 0]) = z;
        *reinterpret_cast<float4*>(&tile[r][cq + 4]) = z;
        *reinterpret_cast<float4*>(&tile[r][cq + 8]) = z;
        *reinterpret_cast<float4*>(&tile[r][cq + 12]) = z;
    }
    __syncthreads();
    int nr = tid >> 2;
    int kq = (tid & 3) * 16;
    u16 hb[16], lb[16];
    #pragma unroll
    for (int i = 0; i < 16; i++) split_bf16(tile[kq + i][nr], hb[i], lb[i]);
    size_t o = ((size_t)b * N_NODES + n0 + nr) * K1P + k0 + kq;
    *reinterpret_cast<uint4*>(xth + o)     = *reinterpret_cast<uint4*>(hb);
    *reinterpret_cast<uint4*>(xth + o + 8) = *reinterpret_cast<uint4*>(hb + 8);
    *reinterpret_cast<uint4*>(xtl + o)     = *reinterpret_cast<uint4*>(lb);
    *reinterpret_cast<uint4*>(xtl + o + 8) = *reinterpret_cast<uint4*>(lb + 8);
}

// ---------------- unified weight prep: base rows 0..351, logit rows 352..359, zero 360..383 ----------------
__global__ void k_prep_wall(const float* __restrict__ W0, const float* __restrict__ W1, const float* __restrict__ W2,
                            const float* __restrict__ as0, const float* __restrict__ as1, const float* __restrict__ as2,
                            const float* __restrict__ ad0, const float* __restrict__ ad1, const float* __restrict__ ad2,
                            u16* __restrict__ h0, u16* __restrict__ l0,
                            u16* __restrict__ h1, u16* __restrict__ l1,
                            u16* __restrict__ h2, u16* __restrict__ l2) {
    int l = blockIdx.y;
    const float* W   = (l == 0) ? W0 : (l == 1) ? W1 : W2;
    const float* as_ = (l == 0) ? as0 : (l == 1) ? as1 : as2;
    const float* ad_ = (l == 0) ? ad0 : (l == 1) ? ad1 : ad2;
    u16* wth = (l == 0) ? h0 : (l == 1) ? h1 : h2;
    u16* wtl = (l == 0) ? l0 : (l == 1) ? l1 : l2;
    int K  = (l == 0) ? FIN_K : HID;
    int KP = (l == 0) ? K1P : HID;
    int n = blockIdx.x;   // 0..383
    if (n < HID) {
        for (int k = threadIdx.x; k < KP; k += 64) {
            float v = (k < K) ? W[(size_t)k * HID + n] : 0.f;
            u16 hi, lo;
            split_bf16(v, hi, lo);
            wth[(size_t)n * KP + k] = hi;
            wtl[(size_t)n * KP + k] = lo;
        }
    } else if (n < 360) {
        int which = n - 352;
        int h = which & 3;
        const float* vec = ((which < 4) ? as_ : ad_) + h * PH;
        for (int k = threadIdx.x; k < KP; k += 64) {
            float acc = 0.f;
            if (k < K) {
                const float* wrow = W + (size_t)k * HID + h * PH;
                #pragma unroll 8
                for (int j = 0; j < PH; j++) acc = fmaf(wrow[j], vec[j], acc);
            }
            u16 hi, lo;
            split_bf16(acc, hi, lo);
            wth[(size_t)n * KP + k] = hi;
            wtl[(size_t)n * KP + k] = lo;
        }
    } else {
        for (int k = threadIdx.x; k < KP; k += 64) {
            wth[(size_t)n * KP + k] = 0;
            wtl[(size_t)n * KP + k] = 0;
        }
    }
}

// ---------------- MFMA GEMM + fused epilogue: bf16 pack + attention logits ----------------
__global__ __launch_bounds__(256) void k_gemm_mfma(
    const u16* __restrict__ Ah, const u16* __restrict__ Al,
    const u16* __restrict__ Bh, const u16* __restrict__ Bl,
    u16* __restrict__ xb16, float* __restrict__ a_s, float* __restrict__ a_d, int K)
{
    __shared__ __align__(16) char smem[24576];
    const int AHo = 0, ALo = 4096, BHo = 8192, BLo = 16384;
    int b = blockIdx.z;
    int m0 = blockIdx.y * 64;
    int n0 = blockIdx.x * 128;
    int tid = threadIdx.x;
    int lane = tid & 63, wid = tid >> 6;
    int wr = (wid >> 1) * 32, wc = (wid & 1) * 64;
    int lrow = lane & 15, kgv = lane >> 4;

    const u16* Abh = Ah + (size_t)b * N_NODES * K;
    const u16* Abl = Al + (size_t)b * N_NODES * K;

    int srow = tid >> 2, skg = tid & 3;
    int sxor = (srow >> 1) & 3;
    int st_lds = srow * 64 + ((skg ^ sxor) << 4);
    int st_lds1 = (srow + 64) * 64 + ((skg ^ sxor) << 4);
    size_t a_g  = (size_t)(m0 + srow) * K + skg * 8;
    size_t b_g0 = (size_t)(n0 + srow) * K + skg * 8;
    size_t b_g1 = (size_t)(n0 + srow + 64) * K + skg * 8;

    int a_ad[2], b_ad[4];
    #pragma unroll
    for (int mf = 0; mf < 2; mf++) {
        int r = wr + mf * 16 + lrow;
        a_ad[mf] = r * 64 + ((kgv ^ ((r >> 1) & 3)) << 4);
    }
    #pragma unroll
    for (int nf = 0; nf < 4; nf++) {
        int c = wc + nf * 16 + lrow;
        b_ad[nf] = c * 64 + ((kgv ^ ((c >> 1) & 3)) << 4);
    }

    f32x4 acc[2][4];
    #pragma unroll
    for (int i = 0; i < 2; i++)
        #pragma unroll
        for (int j = 0; j < 4; j++) acc[i][j] = (f32x4){0.f, 0.f, 0.f, 0.f};

    uint4 cah = *(const uint4*)(Abh + a_g);
    uint4 cal = *(const uint4*)(Abl + a_g);
    uint4 cbh0 = *(const uint4*)(Bh + b_g0);
    uint4 cbl0 = *(const uint4*)(Bl + b_g0);
    uint4 cbh1 = *(const uint4*)(Bh + b_g1);
    uint4 cbl1 = *(const uint4*)(Bl + b_g1);

    for (int k0 = 0; k0 < K; k0 += 32) {
        __syncthreads();
        *(uint4*)(smem + AHo + st_lds) = cah;
        *(uint4*)(smem + ALo + st_lds) = cal;
        *(uint4*)(smem + BHo + st_lds) = cbh0;
        *(uint4*)(smem + BLo + st_lds) = cbl0;
        *(uint4*)(smem + BHo + st_lds1) = cbh1;
        *(uint4*)(smem + BLo + st_lds1) = cbl1;
        int k1 = k0 + 32;
        uint4 nah, nal, nbh0, nbl0, nbh1, nbl1;
        bool more = k1 < K;
        if (more) {
            nah = *(const uint4*)(Abh + a_g + k1);
            nal = *(const uint4*)(Abl + a_g + k1);
            nbh0 = *(const uint4*)(Bh + b_g0 + k1);
            nbl0 = *(const uint4*)(Bl + b_g0 + k1);
            nbh1 = *(const uint4*)(Bh + b_g1 + k1);
            nbl1 = *(const uint4*)(Bl + b_g1 + k1);
        }
        __syncthreads();

        bf16x8 fah0 = *(const bf16x8*)(smem + AHo + a_ad[0]);
        bf16x8 fah1 = *(const bf16x8*)(smem + AHo + a_ad[1]);
        bf16x8 fal0 = *(const bf16x8*)(smem + ALo + a_ad[0]);
        bf16x8 fal1 = *(const bf16x8*)(smem + ALo + a_ad[1]);
        #pragma unroll
        for (int nf = 0; nf < 4; nf++) {
            bf16x8 fbh = *(const bf16x8*)(smem + BHo + b_ad[nf]);
            bf16x8 fbl = *(const bf16x8*)(smem + BLo + b_ad[nf]);
            acc[0][nf] = __builtin_amdgcn_mfma_f32_16x16x32_bf16(fah0, fbh, acc[0][nf], 0, 0, 0);
            acc[1][nf] = __builtin_amdgcn_mfma_f32_16x16x32_bf16(fah1, fbh, acc[1][nf], 0, 0, 0);
            acc[0][nf] = __builtin_amdgcn_mfma_f32_16x16x32_bf16(fal0, fbh, acc[0][nf], 0, 0, 0);
            acc[1][nf] = __builtin_amdgcn_mfma_f32_16x16x32_bf16(fal1, fbh, acc[1][nf], 0, 0, 0);
            acc[0][nf] = __builtin_amdgcn_mfma_f32_16x16x32_bf16(fah0, fbl, acc[0][nf], 0, 0, 0);
            acc[1][nf] = __builtin_amdgcn_mfma_f32_16x16x32_bf16(fah1, fbl, acc[1][nf], 0, 0, 0);
        }
        if (more) { cah = nah; cal = nal; cbh0 = nbh0; cbl0 = nbl0; cbh1 = nbh1; cbl1 = nbl1; }
    }

    #pragma unroll
    for (int nf = 0; nf < 4; nf++) {
        int colg = n0 + wc + nf * 16 + lrow;
        if (colg < HID) {
            #pragma unroll
            for (int mf = 0; mf < 2; mf++) {
                #pragma unroll
                for (int r = 0; r < 4; r++) {
                    int rowg = m0 + wr + mf * 16 + kgv * 4 + r;
                    xb16[((size_t)b * N_NODES + rowg) * HID + colg] = bf16_rne(acc[mf][nf][r]);
                }
            }
        } else if (colg < 360) {
            int which = colg - 352;
            float* dbuf = (which < 4) ? a_s : a_d;
            int hsel = which & 3;
            #pragma unroll
            for (int mf = 0; mf < 2; mf++) {
                #pragma unroll
                for (int r = 0; r < 4; r++) {
                    int rowg = m0 + wr + mf * 16 + kgv * 4 + r;
                    dbuf[((size_t)b * N_NODES + rowg) * 4 + hsel] = acc[mf][nf][r];
                }
            }
        }
    }
}

// ---------------- wave-per-dst aggregation: no LDS, no barriers ----------------
__global__ __launch_bounds__(256) void k_agg(
    const u16* __restrict__ xb16, const float* __restrict__ asrc,
    const float* __restrict__ adst, const int* __restrict__ rp,
    const int* __restrict__ col, const float* __restrict__ bias,
    float* __restrict__ g)
{
    int id = blockIdx.x;
    int xcd = id & 7;
    int gr = xcd >> 1;
    int w = threadIdx.x >> 6;
    int l = threadIdx.x & 63;
    int dst = ((((id >> 3) << 1) | (xcd & 1)) << 2) + w;
    int h = l & 3, slot = l >> 2;
    int beg = rp[dst];
    int deg = rp[dst + 1] - beg;
    const float* asG = asrc + (size_t)gr * N_NODES * NHEAD;
    float my_adst = adst[((size_t)gr * N_NODES + dst) * 4 + h];
    const u32* xb = reinterpret_cast<const u32*>(xb16) + (size_t)gr * N_NODES * 176;

    int c1 = l + 64, c2 = l + 128;
    int hh0 = l / 44, hh1 = c1 / 44, hh2 = c2 / 44;
    bool has2 = (l < 48);
    float2 a0 = {0.f, 0.f}, a1 = {0.f, 0.f}, a2 = {0.f, 0.f};
    float den = 0.f;

    for (int c0 = 0; c0 < deg; c0 += 16) {
        int nthis = min(16, deg - c0);
        int sIdx = col[beg + c0 + ((slot < nthis) ? slot : 0)];
        float xv = asG[sIdx * 4 + h] + my_adst;
        float lg = (xv > 0.f) ? xv : SLOPE * xv;
        float e = (slot < nthis) ? expf(lg) : 0.f;
        den += e;
        int off = sIdx * 176;
        #pragma unroll 2
        for (int i = 0; i < nthis; i++) {
            int offi = __shfl(off, i << 2);
            float e0 = __shfl(e, (i << 2) | hh0);
            float e1 = __shfl(e, (i << 2) | hh1);
            u32 v0 = xb[offi + l];
            u32 v1 = xb[offi + c1];
            a0.x = fmaf(e0, __uint_as_float(v0 << 16), a0.x);
            a0.y = fmaf(e0, __uint_as_float(v0 & 0xFFFF0000u), a0.y);
            a1.x = fmaf(e1, __uint_as_float(v1 << 16), a1.x);
            a1.y = fmaf(e1, __uint_as_float(v1 & 0xFFFF0000u), a1.y);
            if (has2) {
                float e2 = __shfl(e, (i << 2) | hh2);
                u32 v2 = xb[offi + c2];
                a2.x = fmaf(e2, __uint_as_float(v2 << 16), a2.x);
                a2.y = fmaf(e2, __uint_as_float(v2 & 0xFFFF0000u), a2.y);
            }
        }
    }

    den += __shfl_xor(den, 4);
    den += __shfl_xor(den, 8);
    den += __shfl_xor(den, 16);
    den += __shfl_xor(den, 32);
    float inv = 1.0f / den;
    float i0 = __shfl(inv, hh0);
    float i1 = __shfl(inv, hh1);
    float* grow = g + ((size_t)gr * N_NODES + dst) * HID;
    float2 b0 = *reinterpret_cast<const float2*>(bias + 2 * l);
    float2 b1 = *reinterpret_cast<const float2*>(bias + 2 * c1);
    float2 o0 = {a0.x * i0 + b0.x, a0.y * i0 + b0.y};
    float2 o1 = {a1.x * i1 + b1.x, a1.y * i1 + b1.y};
    *reinterpret_cast<float2*>(grow + 2 * l) = o0;
    *reinterpret_cast<float2*>(grow + 2 * c1) = o1;
    if (has2) {
        float i2 = __shfl(inv, hh2);
        float2 b2 = *reinterpret_cast<const float2*>(bias + 2 * c2);
        float2 o2 = {a2.x * i2 + b2.x, a2.y * i2 + b2.y};
        *reinterpret_cast<float2*>(grow + 2 * c2) = o2;
    }
}

// ---------------- GraphNorm split reduce ----------------
__global__ __launch_bounds__(384) void k_reduce(const float* __restrict__ g,
                                                float* __restrict__ ps, float* __restrict__ pss) {
    int b = blockIdx.y, chunk = blockIdx.x;
    int c = threadIdx.x;
    if (c >= HID) return;
    const int ROWS = N_NODES / SPLITS;
    int n0 = chunk * ROWS;
    const float* base = g + ((size_t)b * N_NODES + n0) * HID + c;
    float s = 0.f, ss = 0.f;
    for (int r = 0; r < ROWS; r++) {
        float v = base[(size_t)r * HID];
        s += v;
        ss = fmaf(v, v, ss);
    }
    ps[((size_t)b * SPLITS + chunk) * HID + c] = s;
    pss[((size_t)b * SPLITS + chunk) * HID + c] = ss;
}

__global__ void k_norm_final(const float* __restrict__ ps, const float* __restrict__ pss,
                             const float* __restrict__ ms, const float* __restrict__ w,
                             float* __restrict__ mu_ms, float* __restrict__ scale) {
    int b = blockIdx.x;
    int c = threadIdx.x;
    if (c >= HID) return;
    float s = 0.f, ss = 0.f;
    for (int q = 0; q < SPLITS; q++) {
        s += ps[((size_t)b * SPLITS + q) * HID + c];
        ss += pss[((size_t)b * SPLITS + q) * HID + c];
    }
    float mu = s / (float)N_NODES;
    float Eh2 = ss / (float)N_NODES;
    float msv = ms[c];
    float var = Eh2 - 2.f * msv * mu * mu + msv * msv * mu * mu;
    float rstd = 1.0f / sqrtf(var + EPSV);
    mu_ms[b * HID + c] = msv * mu;
    scale[b * HID + c] = rstd * w[c];
}

// ---------------- apply: norm + residual(from hi/lo) + relu; writes bf16 hi/lo (+opt fp32) ----------------
template<bool RES, bool WBF, bool WOUT>
__global__ void k_apply(const float* __restrict__ g,
                        const float* __restrict__ mu_ms, const float* __restrict__ scale,
                        const float* __restrict__ gnb, float* __restrict__ hout,
                        u16* __restrict__ hh, u16* __restrict__ hl) {
    size_t i2 = (size_t)blockIdx.x * blockDim.x + threadIdx.x;
    size_t total2 = (size_t)B_GR * N_NODES * HID / 2;
    if (i2 >= total2) return;
    size_t e = i2 * 2;
    int c = (int)(e % HID);
    int b = (int)(e / ((size_t)N_NODES * HID));
    float2 v = *reinterpret_cast<const float2*>(g + e);
    float2 mm = *reinterpret_cast<const float2*>(mu_ms + b * HID + c);
    float2 sc = *reinterpret_cast<const float2*>(scale + b * HID + c);
    float2 gb2 = *reinterpret_cast<const float2*>(gnb + c);
    float o0 = (v.x - mm.x) * sc.x + gb2.x;
    float o1 = (v.y - mm.y) * sc.y + gb2.y;
    if (RES) {
        u32 ph = *reinterpret_cast<const u32*>(hh + e);
        u32 pl = *reinterpret_cast<const u32*>(hl + e);
        o0 += __uint_as_float((ph & 0xFFFFu) << 16) + __uint_as_float((pl & 0xFFFFu) << 16);
        o1 += __uint_as_float(ph & 0xFFFF0000u) + __uint_as_float(pl & 0xFFFF0000u);
    }
    o0 = fmaxf(o0, 0.f);
    o1 = fmaxf(o1, 0.f);
    if (WOUT) *reinterpret_cast<float2*>(hout + e) = make_float2(o0, o1);
    if (WBF) {
        u16 h0, l0, h1, l1;
        split_bf16(o0, h0, l0);
        split_bf16(o1, h1, l1);
        *reinterpret_cast<u32*>(hh + e) = (u32)h0 | ((u32)h1 << 16);
        *reinterpret_cast<u32*>(hl + e) = (u32)l0 | ((u32)l1 << 16);
    }
}

// ---------------- pool + classifier ----------------
__global__ __launch_bounds__(384) void k_final(const float* __restrict__ ps,
                                               const float* __restrict__ clfw,
                                               const float* __restrict__ clfb,
                                               float* __restrict__ out) {
    int b = blockIdx.x;
    int t = threadIdx.x;
    __shared__ float buf[384];
    float v = 0.f;
    if (t < HID) {
        float s = 0.f;
        for (int q = 0; q < SPLITS; q++) s += ps[((size_t)b * SPLITS + q) * HID + t];
        v = (s / (float)N_NODES) * clfw[t];
    }
    buf[t] = v;
    __syncthreads();
    if (t < 64) {
        float acc = 0.f;
        for (int j = t; j < 384; j += 64) acc += buf[j];
        for (int off = 32; off; off >>= 1) acc += __shfl_down(acc, off);
        if (t == 0) out[b] = acc + clfb[0];
    }
}

extern "C" void kernel_launch(void* const* d_in, const int* in_sizes, int n_in,
                              void* d_out, int out_size, void* d_ws, size_t ws_size,
                              hipStream_t stream) {
    const float* x = (const float*)d_in[0];
    const int* ei = (const int*)d_in[1];
    const float* W[3]   = {(const float*)d_in[2],  (const float*)d_in[9],  (const float*)d_in[16]};
    const float* as_[3] = {(const float*)d_in[3],  (const float*)d_in[10], (const float*)d_in[17]};
    const float* ad_[3] = {(const float*)d_in[4],  (const float*)d_in[11], (const float*)d_in[18]};
    const float* bi[3]  = {(const float*)d_in[5],  (const float*)d_in[12], (const float*)d_in[19]};
    const float* gw[3]  = {(const float*)d_in[6],  (const float*)d_in[13], (const float*)d_in[20]};
    const float* gb[3]  = {(const float*)d_in[7],  (const float*)d_in[14], (const float*)d_in[21]};
    const float* gms[3] = {(const float*)d_in[8],  (const float*)d_in[15], (const float*)d_in[22]};
    const float* clfw = (const float*)d_in[23];
    const float* clfb = (const float*)d_in[24];
    float* out = (float*)d_out;

    char* ws = (char*)d_ws;
    size_t off = 0;
    auto alloc = [&](size_t bytes) -> void* {
        void* p = ws + off;
        off += (bytes + 255) & ~(size_t)255;
        return p;
    };
    size_t bigf = sizeof(float) * (size_t)B_GR * N_NODES * HID;
    float* gbuf  = (float*)alloc(bigf);
    float* hA    = (float*)alloc(bigf);   // h3 fp32 for pooling
    size_t bfbytes = sizeof(u16) * (size_t)B_GR * N_NODES * K1P;
    u16* bf_hi = (u16*)alloc(bfbytes);
    u16* bf_lo = (u16*)alloc(bfbytes);
    u16* xb16  = (u16*)alloc(sizeof(u16) * (size_t)B_GR * N_NODES * NHEAD * PH);
    u16* wt_h[3]; u16* wt_l[3];
    wt_h[0] = (u16*)alloc(sizeof(u16) * 384 * K1P);
    wt_l[0] = (u16*)alloc(sizeof(u16) * 384 * K1P);
    for (int l = 1; l < 3; l++) {
        wt_h[l] = (u16*)alloc(sizeof(u16) * 384 * HID);
        wt_l[l] = (u16*)alloc(sizeof(u16) * 384 * HID);
    }
    float* a_s   = (float*)alloc(sizeof(float) * B_GR * N_NODES * NHEAD);
    float* a_d   = (float*)alloc(sizeof(float) * B_GR * N_NODES * NHEAD);
    float* ps    = (float*)alloc(sizeof(float) * B_GR * SPLITS * HID);
    float* pss   = (float*)alloc(sizeof(float) * B_GR * SPLITS * HID);
    float* mu_ms = (float*)alloc(sizeof(float) * B_GR * HID);
    float* scale = (float*)alloc(sizeof(float) * B_GR * HID);
    int* rp  = (int*)alloc(sizeof(int) * (N_NODES + 1));
    int* cnt = (int*)alloc(sizeof(int) * N_NODES);
    int* cur = (int*)alloc(sizeof(int) * N_NODES);
    int* col = (int*)alloc(sizeof(int) * ETOT);

    // weight + input prep (2 dispatches)
    k_prep_wall<<<dim3(384, 3), 64, 0, stream>>>(W[0], W[1], W[2],
                                                 as_[0], as_[1], as_[2],
                                                 ad_[0], ad_[1], ad_[2],
                                                 wt_h[0], wt_l[0], wt_h[1], wt_l[1], wt_h[2], wt_l[2]);
    k_prep_x<<<dim3(64, 6, B_GR), 256, 0, stream>>>(x, bf_hi, bf_lo);

    // CSR build (4 dispatches)
    k_zero3<<<(N_NODES + 255) / 256, 256, 0, stream>>>(cnt, cur);
    k_hist<<<(ETOT + 255) / 256, 256, 0, stream>>>(ei, cnt);
    k_scan<<<1, 256, 0, stream>>>(cnt, rp);
    k_scatter<<<(ETOT + 255) / 256, 256, 0, stream>>>(ei, rp, cur, col);

    dim3 ggrid(3, N_NODES / 64, B_GR);
    dim3 rgrid(SPLITS, B_GR);
    size_t total2 = (size_t)B_GR * N_NODES * HID / 2;
    int ablocks = (int)((total2 + 255) / 256);

    for (int l = 0; l < 3; l++) {
        int K = (l == 0) ? K1P : HID;
        k_gemm_mfma<<<ggrid, 256, 0, stream>>>(bf_hi, bf_lo, wt_h[l], wt_l[l], xb16, a_s, a_d, K);
        k_agg<<<B_GR * N_NODES / 4, 256, 0, stream>>>(xb16, a_s, a_d, rp, col, bi[l], gbuf);
        k_reduce<<<rgrid, 384, 0, stream>>>(gbuf, ps, pss);
        k_norm_final<<<B_GR, 384, 0, stream>>>(ps, pss, gms[l], gw[l], mu_ms, scale);
        if (l == 0)      k_apply<false, true,  false><<<ablocks, 256, 0, stream>>>(gbuf, mu_ms, scale, gb[l], hA, bf_hi, bf_lo);
        else if (l == 1) k_apply<true,  true,  false><<<ablocks, 256, 0, stream>>>(gbuf, mu_ms, scale, gb[l], hA, bf_hi, bf_lo);
        else             k_apply<true,  false, true ><<<ablocks, 256, 0, stream>>>(gbuf, mu_ms, scale, gb[l], hA, bf_hi, bf_lo);
    }
    k_reduce<<<rgrid, 384, 0, stream>>>(hA, ps, pss);
    k_final<<<B_GR, 384, 0, stream>>>(ps, clfw, clfb, out);
}

// Round 13
// 268.188 us; speedup vs baseline: 1.4895x; 1.0346x over previous
//
#include <hip/hip_runtime.h>
#include <math.h>

#define N_NODES 4096
#define B_GR 4
#define FIN_K 354
#define K1P 384
#define HID 352
#define NHEAD 4
#define PH 88
#define E_EDGES 65536
#define ETOT (E_EDGES + N_NODES)
#define EPSV 1e-5f
#define SLOPE 0.2f
#define SPLITS 64

typedef unsigned short u16;
typedef unsigned int u32;
typedef __attribute__((ext_vector_type(8))) short bf16x8;
typedef __attribute__((ext_vector_type(4))) float f32x4;

__device__ __forceinline__ void split_bf16(float v, u16& hi, u16& lo) {
    u32 u = __float_as_uint(v);
    hi = (u16)(u >> 16);
    float rem = v - __uint_as_float(((u32)hi) << 16);
    lo = (u16)(__float_as_uint(rem) >> 16);
}

__device__ __forceinline__ u16 bf16_rne(float v) {
    u32 u = __float_as_uint(v);
    u32 r = u + 0x7FFFu + ((u >> 16) & 1u);
    return (u16)(r >> 16);
}

// XCD affinity: graph g owns XCD pair (2g, 2g+1); blockIdx%8 == XCD (measured R6: FETCH 164->14.8MB)
__device__ __forceinline__ void xcd_map(int id, int& gr, int& q) {
    int xcd = id & 7;
    gr = xcd >> 1;
    q = ((id >> 3) << 1) | (xcd & 1);
}

// ---------------- CSR build ----------------
__global__ void k_zero3(int* __restrict__ cnt, int* __restrict__ cur) {
    int i = blockIdx.x * blockDim.x + threadIdx.x;
    if (i < N_NODES) { cnt[i] = 0; cur[i] = 0; }
}

__global__ void k_hist(const int* __restrict__ ei, int* __restrict__ cnt) {
    int e = blockIdx.x * blockDim.x + threadIdx.x;
    if (e >= ETOT) return;
    int dst = (e < E_EDGES) ? ei[E_EDGES + e] : (e - E_EDGES);
    atomicAdd(&cnt[dst], 1);
}

__global__ void k_scan(const int* __restrict__ cnt, int* __restrict__ rp) {
    __shared__ int tot[256];
    int t = threadIdx.x;
    int base = t * 16;
    int loc[16];
    int s = 0;
    #pragma unroll
    for (int i = 0; i < 16; i++) { loc[i] = s; s += cnt[base + i]; }
    tot[t] = s;
    __syncthreads();
    for (int off = 1; off < 256; off <<= 1) {
        int v = (t >= off) ? tot[t - off] : 0;
        __syncthreads();
        tot[t] += v;
        __syncthreads();
    }
    int excl = (t == 0) ? 0 : tot[t - 1];
    #pragma unroll
    for (int i = 0; i < 16; i++) rp[base + i] = excl + loc[i];
    if (t == 255) rp[N_NODES] = tot[255];
}

__global__ void k_scatter(const int* __restrict__ ei, const int* __restrict__ rp,
                          int* __restrict__ cur, int* __restrict__ col) {
    int e = blockIdx.x * blockDim.x + threadIdx.x;
    if (e >= ETOT) return;
    int src, dst;
    if (e < E_EDGES) { src = ei[e]; dst = ei[E_EDGES + e]; }
    else { src = e - E_EDGES; dst = src; }
    int pos = rp[dst] + atomicAdd(&cur[dst], 1);
    col[pos] = src;
}

// ---------------- input conversion: x[B][FIN][N] -> XT hi/lo [B][N][384]; XCD-affine ----------------
__global__ __launch_bounds__(256) void k_prep_x(const float* __restrict__ x,
                                                u16* __restrict__ xth, u16* __restrict__ xtl) {
    __shared__ float tile[64][65];
    int b, q;
    xcd_map(blockIdx.x, b, q);          // q in 0..383
    int n0 = (q & 63) * 64;
    int k0 = (q >> 6) * 64;
    int tid = threadIdx.x;
    int r = tid >> 2;
    int cq = (tid & 3) * 16;
    int kglob = k0 + r;
    if (kglob < FIN_K) {
        const float* src = x + ((size_t)b * FIN_K + kglob) * N_NODES + n0 + cq;
        float4 v0 = *reinterpret_cast<const float4*>(src + 0);
        float4 v1 = *reinterpret_cast<const float4*>(src + 4);
        float4 v2 = *reinterpret_cast<const float4*>(src + 8);
        float4 v3 = *reinterpret_cast<const float4*>(src + 12);
        *reinterpret_cast<float4*>(&tile[r][cq + 0]) = v0;
        *reinterpret_cast<float4*>(&tile[r][cq + 4]) = v1;
        *reinterpret_cast<float4*>(&tile[r][cq + 8]) = v2;
        *reinterpret_cast<float4*>(&tile[r][cq + 12]) = v3;
    } else {
        float4 z = make_float4(0.f, 0.f, 0.f, 0.f);
        *reinterpret_cast<float4*>(&tile[r][cq + 0]) = z;
        *reinterpret_cast<float4*>(&tile[r][cq + 4]) = z;
        *reinterpret_cast<float4*>(&tile[r][cq + 8]) = z;
        *reinterpret_cast<float4*>(&tile[r][cq + 12]) = z;
    }
    __syncthreads();
    int nr = tid >> 2;
    int kq = (tid & 3) * 16;
    u16 hb[16], lb[16];
    #pragma unroll
    for (int i = 0; i < 16; i++) split_bf16(tile[kq + i][nr], hb[i], lb[i]);
    size_t o = ((size_t)b * N_NODES + n0 + nr) * K1P + k0 + kq;
    *reinterpret_cast<uint4*>(xth + o)     = *reinterpret_cast<uint4*>(hb);
    *reinterpret_cast<uint4*>(xth + o + 8) = *reinterpret_cast<uint4*>(hb + 8);
    *reinterpret_cast<uint4*>(xtl + o)     = *reinterpret_cast<uint4*>(lb);
    *reinterpret_cast<uint4*>(xtl + o + 8) = *reinterpret_cast<uint4*>(lb + 8);
}

// ---------------- unified weight prep: base rows 0..351, logit rows 352..359, zero 360..383 ----------------
__global__ void k_prep_wall(const float* __restrict__ W0, const float* __restrict__ W1, const float* __restrict__ W2,
                            const float* __restrict__ as0, const float* __restrict__ as1, const float* __restrict__ as2,
                            const float* __restrict__ ad0, const float* __restrict__ ad1, const float* __restrict__ ad2,
                            u16* __restrict__ h0, u16* __restrict__ l0,
                            u16* __restrict__ h1, u16* __restrict__ l1,
                            u16* __restrict__ h2, u16* __restrict__ l2) {
    int l = blockIdx.y;
    const float* W   = (l == 0) ? W0 : (l == 1) ? W1 : W2;
    const float* as_ = (l == 0) ? as0 : (l == 1) ? as1 : as2;
    const float* ad_ = (l == 0) ? ad0 : (l == 1) ? ad1 : ad2;
    u16* wth = (l == 0) ? h0 : (l == 1) ? h1 : h2;
    u16* wtl = (l == 0) ? l0 : (l == 1) ? l1 : l2;
    int K  = (l == 0) ? FIN_K : HID;
    int KP = (l == 0) ? K1P : HID;
    int n = blockIdx.x;   // 0..383
    if (n < HID) {
        for (int k = threadIdx.x; k < KP; k += 64) {
            float v = (k < K) ? W[(size_t)k * HID + n] : 0.f;
            u16 hi, lo;
            split_bf16(v, hi, lo);
            wth[(size_t)n * KP + k] = hi;
            wtl[(size_t)n * KP + k] = lo;
        }
    } else if (n < 360) {
        int which = n - 352;
        int h = which & 3;
        const float* vec = ((which < 4) ? as_ : ad_) + h * PH;
        for (int k = threadIdx.x; k < KP; k += 64) {
            float acc = 0.f;
            if (k < K) {
                const float* wrow = W + (size_t)k * HID + h * PH;
                #pragma unroll 8
                for (int j = 0; j < PH; j++) acc = fmaf(wrow[j], vec[j], acc);
            }
            u16 hi, lo;
            split_bf16(acc, hi, lo);
            wth[(size_t)n * KP + k] = hi;
            wtl[(size_t)n * KP + k] = lo;
        }
    } else {
        for (int k = threadIdx.x; k < KP; k += 64) {
            wth[(size_t)n * KP + k] = 0;
            wtl[(size_t)n * KP + k] = 0;
        }
    }
}

// ---------------- MFMA GEMM + fused epilogue; XCD-affine block mapping ----------------
__global__ __launch_bounds__(256) void k_gemm_mfma(
    const u16* __restrict__ Ah, const u16* __restrict__ Al,
    const u16* __restrict__ Bh, const u16* __restrict__ Bl,
    u16* __restrict__ xb16, float* __restrict__ a_s, float* __restrict__ a_d, int K)
{
    __shared__ __align__(16) char smem[24576];
    const int AHo = 0, ALo = 4096, BHo = 8192, BLo = 16384;
    int b, q;
    xcd_map(blockIdx.x, b, q);          // q in 0..191: 3 n-tiles x 64 m-tiles
    int n0 = (q % 3) * 128;
    int m0 = (q / 3) * 64;
    int tid = threadIdx.x;
    int lane = tid & 63, wid = tid >> 6;
    int wr = (wid >> 1) * 32, wc = (wid & 1) * 64;
    int lrow = lane & 15, kgv = lane >> 4;

    const u16* Abh = Ah + (size_t)b * N_NODES * K;
    const u16* Abl = Al + (size_t)b * N_NODES * K;

    int srow = tid >> 2, skg = tid & 3;
    int sxor = (srow >> 1) & 3;
    int st_lds = srow * 64 + ((skg ^ sxor) << 4);
    int st_lds1 = (srow + 64) * 64 + ((skg ^ sxor) << 4);
    size_t a_g  = (size_t)(m0 + srow) * K + skg * 8;
    size_t b_g0 = (size_t)(n0 + srow) * K + skg * 8;
    size_t b_g1 = (size_t)(n0 + srow + 64) * K + skg * 8;

    int a_ad[2], b_ad[4];
    #pragma unroll
    for (int mf = 0; mf < 2; mf++) {
        int r = wr + mf * 16 + lrow;
        a_ad[mf] = r * 64 + ((kgv ^ ((r >> 1) & 3)) << 4);
    }
    #pragma unroll
    for (int nf = 0; nf < 4; nf++) {
        int c = wc + nf * 16 + lrow;
        b_ad[nf] = c * 64 + ((kgv ^ ((c >> 1) & 3)) << 4);
    }

    f32x4 acc[2][4];
    #pragma unroll
    for (int i = 0; i < 2; i++)
        #pragma unroll
        for (int j = 0; j < 4; j++) acc[i][j] = (f32x4){0.f, 0.f, 0.f, 0.f};

    uint4 cah = *(const uint4*)(Abh + a_g);
    uint4 cal = *(const uint4*)(Abl + a_g);
    uint4 cbh0 = *(const uint4*)(Bh + b_g0);
    uint4 cbl0 = *(const uint4*)(Bl + b_g0);
    uint4 cbh1 = *(const uint4*)(Bh + b_g1);
    uint4 cbl1 = *(const uint4*)(Bl + b_g1);

    for (int k0 = 0; k0 < K; k0 += 32) {
        __syncthreads();
        *(uint4*)(smem + AHo + st_lds) = cah;
        *(uint4*)(smem + ALo + st_lds) = cal;
        *(uint4*)(smem + BHo + st_lds) = cbh0;
        *(uint4*)(smem + BLo + st_lds) = cbl0;
        *(uint4*)(smem + BHo + st_lds1) = cbh1;
        *(uint4*)(smem + BLo + st_lds1) = cbl1;
        int k1 = k0 + 32;
        uint4 nah, nal, nbh0, nbl0, nbh1, nbl1;
        bool more = k1 < K;
        if (more) {
            nah = *(const uint4*)(Abh + a_g + k1);
            nal = *(const uint4*)(Abl + a_g + k1);
            nbh0 = *(const uint4*)(Bh + b_g0 + k1);
            nbl0 = *(const uint4*)(Bl + b_g0 + k1);
            nbh1 = *(const uint4*)(Bh + b_g1 + k1);
            nbl1 = *(const uint4*)(Bl + b_g1 + k1);
        }
        __syncthreads();

        bf16x8 fah0 = *(const bf16x8*)(smem + AHo + a_ad[0]);
        bf16x8 fah1 = *(const bf16x8*)(smem + AHo + a_ad[1]);
        bf16x8 fal0 = *(const bf16x8*)(smem + ALo + a_ad[0]);
        bf16x8 fal1 = *(const bf16x8*)(smem + ALo + a_ad[1]);
        #pragma unroll
        for (int nf = 0; nf < 4; nf++) {
            bf16x8 fbh = *(const bf16x8*)(smem + BHo + b_ad[nf]);
            bf16x8 fbl = *(const bf16x8*)(smem + BLo + b_ad[nf]);
            acc[0][nf] = __builtin_amdgcn_mfma_f32_16x16x32_bf16(fah0, fbh, acc[0][nf], 0, 0, 0);
            acc[1][nf] = __builtin_amdgcn_mfma_f32_16x16x32_bf16(fah1, fbh, acc[1][nf], 0, 0, 0);
            acc[0][nf] = __builtin_amdgcn_mfma_f32_16x16x32_bf16(fal0, fbh, acc[0][nf], 0, 0, 0);
            acc[1][nf] = __builtin_amdgcn_mfma_f32_16x16x32_bf16(fal1, fbh, acc[1][nf], 0, 0, 0);
            acc[0][nf] = __builtin_amdgcn_mfma_f32_16x16x32_bf16(fah0, fbl, acc[0][nf], 0, 0, 0);
            acc[1][nf] = __builtin_amdgcn_mfma_f32_16x16x32_bf16(fah1, fbl, acc[1][nf], 0, 0, 0);
        }
        if (more) { cah = nah; cal = nal; cbh0 = nbh0; cbl0 = nbl0; cbh1 = nbh1; cbl1 = nbl1; }
    }

    #pragma unroll
    for (int nf = 0; nf < 4; nf++) {
        int colg = n0 + wc + nf * 16 + lrow;
        if (colg < HID) {
            #pragma unroll
            for (int mf = 0; mf < 2; mf++) {
                #pragma unroll
                for (int r = 0; r < 4; r++) {
                    int rowg = m0 + wr + mf * 16 + kgv * 4 + r;
                    xb16[((size_t)b * N_NODES + rowg) * HID + colg] = bf16_rne(acc[mf][nf][r]);
                }
            }
        } else if (colg < 360) {
            int which = colg - 352;
            float* dbuf = (which < 4) ? a_s : a_d;
            int hsel = which & 3;
            #pragma unroll
            for (int mf = 0; mf < 2; mf++) {
                #pragma unroll
                for (int r = 0; r < 4; r++) {
                    int rowg = m0 + wr + mf * 16 + kgv * 4 + r;
                    dbuf[((size_t)b * N_NODES + rowg) * 4 + hsel] = acc[mf][nf][r];
                }
            }
        }
    }
}

// ---------------- wave-per-dst aggregation: no LDS, no barriers; XCD-affine ----------------
__global__ __launch_bounds__(256) void k_agg(
    const u16* __restrict__ xb16, const float* __restrict__ asrc,
    const float* __restrict__ adst, const int* __restrict__ rp,
    const int* __restrict__ col, const float* __restrict__ bias,
    float* __restrict__ g)
{
    int gr, q;
    xcd_map(blockIdx.x, gr, q);
    int w = threadIdx.x >> 6;
    int l = threadIdx.x & 63;
    int dst = (q << 2) + w;
    int h = l & 3, slot = l >> 2;
    int beg = rp[dst];
    int deg = rp[dst + 1] - beg;
    const float* asG = asrc + (size_t)gr * N_NODES * NHEAD;
    float my_adst = adst[((size_t)gr * N_NODES + dst) * 4 + h];
    const u32* xb = reinterpret_cast<const u32*>(xb16) + (size_t)gr * N_NODES * 176;

    int c1 = l + 64, c2 = l + 128;
    int hh0 = l / 44, hh1 = c1 / 44, hh2 = c2 / 44;
    bool has2 = (l < 48);
    float2 a0 = {0.f, 0.f}, a1 = {0.f, 0.f}, a2 = {0.f, 0.f};
    float den = 0.f;

    for (int c0 = 0; c0 < deg; c0 += 16) {
        int nthis = min(16, deg - c0);
        int sIdx = col[beg + c0 + ((slot < nthis) ? slot : 0)];
        float xv = asG[sIdx * 4 + h] + my_adst;
        float lg = (xv > 0.f) ? xv : SLOPE * xv;
        float e = (slot < nthis) ? expf(lg) : 0.f;
        den += e;
        int off = sIdx * 176;
        #pragma unroll 2
        for (int i = 0; i < nthis; i++) {
            int offi = __shfl(off, i << 2);
            float e0 = __shfl(e, (i << 2) | hh0);
            float e1 = __shfl(e, (i << 2) | hh1);
            u32 v0 = xb[offi + l];
            u32 v1 = xb[offi + c1];
            a0.x = fmaf(e0, __uint_as_float(v0 << 16), a0.x);
            a0.y = fmaf(e0, __uint_as_float(v0 & 0xFFFF0000u), a0.y);
            a1.x = fmaf(e1, __uint_as_float(v1 << 16), a1.x);
            a1.y = fmaf(e1, __uint_as_float(v1 & 0xFFFF0000u), a1.y);
            if (has2) {
                float e2 = __shfl(e, (i << 2) | hh2);
                u32 v2 = xb[offi + c2];
                a2.x = fmaf(e2, __uint_as_float(v2 << 16), a2.x);
                a2.y = fmaf(e2, __uint_as_float(v2 & 0xFFFF0000u), a2.y);
            }
        }
    }

    den += __shfl_xor(den, 4);
    den += __shfl_xor(den, 8);
    den += __shfl_xor(den, 16);
    den += __shfl_xor(den, 32);
    float inv = 1.0f / den;
    float i0 = __shfl(inv, hh0);
    float i1 = __shfl(inv, hh1);
    float* grow = g + ((size_t)gr * N_NODES + dst) * HID;
    float2 b0 = *reinterpret_cast<const float2*>(bias + 2 * l);
    float2 b1 = *reinterpret_cast<const float2*>(bias + 2 * c1);
    float2 o0 = {a0.x * i0 + b0.x, a0.y * i0 + b0.y};
    float2 o1 = {a1.x * i1 + b1.x, a1.y * i1 + b1.y};
    *reinterpret_cast<float2*>(grow + 2 * l) = o0;
    *reinterpret_cast<float2*>(grow + 2 * c1) = o1;
    if (has2) {
        float i2 = __shfl(inv, hh2);
        float2 b2 = *reinterpret_cast<const float2*>(bias + 2 * c2);
        float2 o2 = {a2.x * i2 + b2.x, a2.y * i2 + b2.y};
        *reinterpret_cast<float2*>(grow + 2 * c2) = o2;
    }
}

// ---------------- GraphNorm split reduce; XCD-affine ----------------
__global__ __launch_bounds__(384) void k_reduce(const float* __restrict__ g,
                                                float* __restrict__ ps, float* __restrict__ pss) {
    int b, chunk;
    xcd_map(blockIdx.x, b, chunk);      // chunk in 0..63
    int c = threadIdx.x;
    if (c >= HID) return;
    const int ROWS = N_NODES / SPLITS;
    int n0 = chunk * ROWS;
    const float* base = g + ((size_t)b * N_NODES + n0) * HID + c;
    float s = 0.f, ss = 0.f;
    for (int r = 0; r < ROWS; r++) {
        float v = base[(size_t)r * HID];
        s += v;
        ss = fmaf(v, v, ss);
    }
    ps[((size_t)b * SPLITS + chunk) * HID + c] = s;
    pss[((size_t)b * SPLITS + chunk) * HID + c] = ss;
}

__global__ void k_norm_final(const float* __restrict__ ps, const float* __restrict__ pss,
                             const float* __restrict__ ms, const float* __restrict__ w,
                             float* __restrict__ mu_ms, float* __restrict__ scale) {
    int b = blockIdx.x;
    int c = threadIdx.x;
    if (c >= HID) return;
    float s = 0.f, ss = 0.f;
    for (int q = 0; q < SPLITS; q++) {
        s += ps[((size_t)b * SPLITS + q) * HID + c];
        ss += pss[((size_t)b * SPLITS + q) * HID + c];
    }
    float mu = s / (float)N_NODES;
    float Eh2 = ss / (float)N_NODES;
    float msv = ms[c];
    float var = Eh2 - 2.f * msv * mu * mu + msv * msv * mu * mu;
    float rstd = 1.0f / sqrtf(var + EPSV);
    mu_ms[b * HID + c] = msv * mu;
    scale[b * HID + c] = rstd * w[c];
}

// ---------------- apply: norm + residual(from hi/lo) + relu; XCD-affine ----------------
template<bool RES, bool WBF, bool WOUT>
__global__ void k_apply(const float* __restrict__ g,
                        const float* __restrict__ mu_ms, const float* __restrict__ scale,
                        const float* __restrict__ gnb, float* __restrict__ hout,
                        u16* __restrict__ hh, u16* __restrict__ hl) {
    int b, q;
    xcd_map(blockIdx.x, b, q);          // q in 0..2815 per graph
    int local2 = q * 256 + threadIdx.x; // pair index within graph
    size_t e = (size_t)b * N_NODES * HID + (size_t)local2 * 2;
    int c = (local2 * 2) % HID;
    float2 v = *reinterpret_cast<const float2*>(g + e);
    float2 mm = *reinterpret_cast<const float2*>(mu_ms + b * HID + c);
    float2 sc = *reinterpret_cast<const float2*>(scale + b * HID + c);
    float2 gb2 = *reinterpret_cast<const float2*>(gnb + c);
    float o0 = (v.x - mm.x) * sc.x + gb2.x;
    float o1 = (v.y - mm.y) * sc.y + gb2.y;
    if (RES) {
        u32 ph = *reinterpret_cast<const u32*>(hh + e);
        u32 pl = *reinterpret_cast<const u32*>(hl + e);
        o0 += __uint_as_float((ph & 0xFFFFu) << 16) + __uint_as_float((pl & 0xFFFFu) << 16);
        o1 += __uint_as_float(ph & 0xFFFF0000u) + __uint_as_float(pl & 0xFFFF0000u);
    }
    o0 = fmaxf(o0, 0.f);
    o1 = fmaxf(o1, 0.f);
    if (WOUT) *reinterpret_cast<float2*>(hout + e) = make_float2(o0, o1);
    if (WBF) {
        u16 h0, l0, h1, l1;
        split_bf16(o0, h0, l0);
        split_bf16(o1, h1, l1);
        *reinterpret_cast<u32*>(hh + e) = (u32)h0 | ((u32)h1 << 16);
        *reinterpret_cast<u32*>(hl + e) = (u32)l0 | ((u32)l1 << 16);
    }
}

// ---------------- pool + classifier ----------------
__global__ __launch_bounds__(384) void k_final(const float* __restrict__ ps,
                                               const float* __restrict__ clfw,
                                               const float* __restrict__ clfb,
                                               float* __restrict__ out) {
    int b = blockIdx.x;
    int t = threadIdx.x;
    __shared__ float buf[384];
    float v = 0.f;
    if (t < HID) {
        float s = 0.f;
        for (int q = 0; q < SPLITS; q++) s += ps[((size_t)b * SPLITS + q) * HID + t];
        v = (s / (float)N_NODES) * clfw[t];
    }
    buf[t] = v;
    __syncthreads();
    if (t < 64) {
        float acc = 0.f;
        for (int j = t; j < 384; j += 64) acc += buf[j];
        for (int off = 32; off; off >>= 1) acc += __shfl_down(acc, off);
        if (t == 0) out[b] = acc + clfb[0];
    }
}

extern "C" void kernel_launch(void* const* d_in, const int* in_sizes, int n_in,
                              void* d_out, int out_size, void* d_ws, size_t ws_size,
                              hipStream_t stream) {
    const float* x = (const float*)d_in[0];
    const int* ei = (const int*)d_in[1];
    const float* W[3]   = {(const float*)d_in[2],  (const float*)d_in[9],  (const float*)d_in[16]};
    const float* as_[3] = {(const float*)d_in[3],  (const float*)d_in[10], (const float*)d_in[17]};
    const float* ad_[3] = {(const float*)d_in[4],  (const float*)d_in[11], (const float*)d_in[18]};
    const float* bi[3]  = {(const float*)d_in[5],  (const float*)d_in[12], (const float*)d_in[19]};
    const float* gw[3]  = {(const float*)d_in[6],  (const float*)d_in[13], (const float*)d_in[20]};
    const float* gb[3]  = {(const float*)d_in[7],  (const float*)d_in[14], (const float*)d_in[21]};
    const float* gms[3] = {(const float*)d_in[8],  (const float*)d_in[15], (const float*)d_in[22]};
    const float* clfw = (const float*)d_in[23];
    const float* clfb = (const float*)d_in[24];
    float* out = (float*)d_out;

    char* ws = (char*)d_ws;
    size_t off = 0;
    auto alloc = [&](size_t bytes) -> void* {
        void* p = ws + off;
        off += (bytes + 255) & ~(size_t)255;
        return p;
    };
    size_t bigf = sizeof(float) * (size_t)B_GR * N_NODES * HID;
    float* gbuf  = (float*)alloc(bigf);
    float* hA    = (float*)alloc(bigf);   // h3 fp32 for pooling
    size_t bfbytes = sizeof(u16) * (size_t)B_GR * N_NODES * K1P;
    u16* bf_hi = (u16*)alloc(bfbytes);
    u16* bf_lo = (u16*)alloc(bfbytes);
    u16* xb16  = (u16*)alloc(sizeof(u16) * (size_t)B_GR * N_NODES * NHEAD * PH);
    u16* wt_h[3]; u16* wt_l[3];
    wt_h[0] = (u16*)alloc(sizeof(u16) * 384 * K1P);
    wt_l[0] = (u16*)alloc(sizeof(u16) * 384 * K1P);
    for (int l = 1; l < 3; l++) {
        wt_h[l] = (u16*)alloc(sizeof(u16) * 384 * HID);
        wt_l[l] = (u16*)alloc(sizeof(u16) * 384 * HID);
    }
    float* a_s   = (float*)alloc(sizeof(float) * B_GR * N_NODES * NHEAD);
    float* a_d   = (float*)alloc(sizeof(float) * B_GR * N_NODES * NHEAD);
    float* ps    = (float*)alloc(sizeof(float) * B_GR * SPLITS * HID);
    float* pss   = (float*)alloc(sizeof(float) * B_GR * SPLITS * HID);
    float* mu_ms = (float*)alloc(sizeof(float) * B_GR * HID);
    float* scale = (float*)alloc(sizeof(float) * B_GR * HID);
    int* rp  = (int*)alloc(sizeof(int) * (N_NODES + 1));
    int* cnt = (int*)alloc(sizeof(int) * N_NODES);
    int* cur = (int*)alloc(sizeof(int) * N_NODES);
    int* col = (int*)alloc(sizeof(int) * ETOT);

    // weight + input prep (2 dispatches)
    k_prep_wall<<<dim3(384, 3), 64, 0, stream>>>(W[0], W[1], W[2],
                                                 as_[0], as_[1], as_[2],
                                                 ad_[0], ad_[1], ad_[2],
                                                 wt_h[0], wt_l[0], wt_h[1], wt_l[1], wt_h[2], wt_l[2]);
    k_prep_x<<<B_GR * 384, 256, 0, stream>>>(x, bf_hi, bf_lo);

    // CSR build (4 dispatches)
    k_zero3<<<(N_NODES + 255) / 256, 256, 0, stream>>>(cnt, cur);
    k_hist<<<(ETOT + 255) / 256, 256, 0, stream>>>(ei, cnt);
    k_scan<<<1, 256, 0, stream>>>(cnt, rp);
    k_scatter<<<(ETOT + 255) / 256, 256, 0, stream>>>(ei, rp, cur, col);

    for (int l = 0; l < 3; l++) {
        int K = (l == 0) ? K1P : HID;
        k_gemm_mfma<<<B_GR * 192, 256, 0, stream>>>(bf_hi, bf_lo, wt_h[l], wt_l[l], xb16, a_s, a_d, K);
        k_agg<<<B_GR * N_NODES / 4, 256, 0, stream>>>(xb16, a_s, a_d, rp, col, bi[l], gbuf);
        k_reduce<<<B_GR * SPLITS, 384, 0, stream>>>(gbuf, ps, pss);
        k_norm_final<<<B_GR, 384, 0, stream>>>(ps, pss, gms[l], gw[l], mu_ms, scale);
        if (l == 0)      k_apply<false, true,  false><<<B_GR * 2816, 256, 0, stream>>>(gbuf, mu_ms, scale, gb[l], hA, bf_hi, bf_lo);
        else if (l == 1) k_apply<true,  true,  false><<<B_GR * 2816, 256, 0, stream>>>(gbuf, mu_ms, scale, gb[l], hA, bf_hi, bf_lo);
        else             k_apply<true,  false, true ><<<B_GR * 2816, 256, 0, stream>>>(gbuf, mu_ms, scale, gb[l], hA, bf_hi, bf_lo);
    }
    k_reduce<<<B_GR * SPLITS, 384, 0, stream>>>(hA, ps, pss);
    k_final<<<B_GR, 384, 0, stream>>>(ps, clfw, clfb, out);
}